// Round 2
// baseline (193.407 us; speedup 1.0000x reference)
//
#include <hip/hip_runtime.h>

typedef __attribute__((ext_vector_type(8))) short short8;
typedef __attribute__((ext_vector_type(4))) short short4v;
typedef __attribute__((ext_vector_type(4))) float float4v;

#define MFMA16(a, b, c) __builtin_amdgcn_mfma_f32_16x16x32_bf16((a), (b), (c), 0, 0, 0)

constexpr int kN = 512;
constexpr int kD = 64;
constexpr int kThreads = 512;

// LDS layout (ushort elements):
//   [0,      32768)  K swizzled bf16 (B-operand for QK^T, channel-contiguous):
//                      elem (n,d) at (d>>3)*4096 + n*8 + (d&7)
//   [32768,  65536)  V swizzled bf16 (B-operand for PV, POSITION-contiguous):
//                      elem (n,d) at (n>>3)*512 + d*8 + (n&7)
//   [65536,  69632)  Wd swizzled bf16: elem (d,e) at (d>>3)*512 + e*8 + (d&7)
//   [69632,  81920)  region R: Wq/Wk/Wv staging (3*4096) during phase 1,
//                    reused as 8 per-wave repack buffers (16 rows x 72, padded) in phase 2/3
constexpr int LDS_TOTAL_BYTES = 163840;  // 160 KiB — 1 block/CU

static __device__ __forceinline__ unsigned short f2bf(float f) {
  // round-to-nearest-even fp32 -> bf16
  unsigned int u = __float_as_uint(f);
  u = (u + 0x7fffu + ((u >> 16) & 1u)) >> 16;
  return (unsigned short)u;
}

__global__ __launch_bounds__(kThreads, 2) void ts_attn_fused(
    const float* __restrict__ x, const float* __restrict__ Wq_t,
    const float* __restrict__ Wk_t, const float* __restrict__ Wv_t,
    const float* __restrict__ Wq_s, const float* __restrict__ Wk_s,
    const float* __restrict__ Wv_s, const float* __restrict__ Wd_t,
    const float* __restrict__ bd_t, const float* __restrict__ Wd_s,
    const float* __restrict__ bd_s, float* __restrict__ out,
    unsigned short* __restrict__ qws) {
  extern __shared__ __align__(16) unsigned short smem_us[];
  unsigned short* Ksw = smem_us;           // 32768 elems
  unsigned short* Vsw = smem_us + 32768;   // 32768 elems
  unsigned short* Wdsw = smem_us + 65536;  // 4096 elems
  unsigned short* Rreg = smem_us + 69632;  // 12288 elems

  const int tid = threadIdx.x;
  const int wv = tid >> 6;   // wave 0..7
  const int lane = tid & 63;
  const int ln = lane & 15;  // "column"/row-of-16 index
  const int quad = lane >> 4;
  const int b = blockIdx.x;

  const float* xb = x + (size_t)b * (kN * kD);
  float* outb = out + (size_t)b * (kN * kD);
  unsigned short* qb = qws + (size_t)b * (kN * kD);  // per-batch 64 KB of Q (bf16, A-swizzle)

  // bias preload: epilogue lane covers cols e = nt*16 + ln
  float bdsum[4];
#pragma unroll
  for (int nt = 0; nt < 4; ++nt) bdsum[nt] = bd_t[nt * 16 + ln] + bd_s[nt * 16 + ln];

#pragma unroll 1
  for (int br = 0; br < 2; ++br) {
    const float* Wq = br ? Wq_s : Wq_t;
    const float* Wk = br ? Wk_s : Wk_t;
    const float* Wv = br ? Wv_s : Wv_t;
    const float* Wd = br ? Wd_s : Wd_t;

    // ---- stage the 4 weight matrices into LDS (bf16, B-operand swizzle) ----
    {
      const int d = tid >> 3;           // 0..63
      const int e0 = (tid & 7) * 8;     // 0..56
      const int base = (d >> 3) * 512 + (d & 7);
      const float* srcs[4] = {Wq, Wk, Wv, Wd};
      unsigned short* dsts[4] = {Rreg, Rreg + 4096, Rreg + 8192, Wdsw};
#pragma unroll
      for (int g = 0; g < 4; ++g) {
        const float4v* p = reinterpret_cast<const float4v*>(srcs[g] + d * 64 + e0);
        const float4v u = p[0];
        const float4v v = p[1];
        unsigned short* dst = dsts[g];
#pragma unroll
        for (int i = 0; i < 4; ++i) dst[base + (e0 + i) * 8] = f2bf(u[i]);
#pragma unroll
        for (int i = 0; i < 4; ++i) dst[base + (e0 + 4 + i) * 8] = f2bf(v[i]);
      }
    }
    __syncthreads();

    // ---- phase 1: Q,K,V = X @ W (MFMA). K,V -> LDS; Q -> global ws ----
#pragma unroll 1
    for (int mi = 0; mi < 4; ++mi) {
      const int mt = wv + mi * 8;  // m-tile 0..31
      const int mrow = mt * 16 + ln;
      short8 xa0, xa1;
      {
        const float4v* p0 = reinterpret_cast<const float4v*>(xb + mrow * 64 + quad * 8);
        const float4v u0 = p0[0], v0 = p0[1];
        const float4v* p1 = reinterpret_cast<const float4v*>(xb + mrow * 64 + 32 + quad * 8);
        const float4v u1 = p1[0], v1 = p1[1];
#pragma unroll
        for (int i = 0; i < 4; ++i) {
          xa0[i] = (short)f2bf(u0[i]);
          xa0[4 + i] = (short)f2bf(v0[i]);
          xa1[i] = (short)f2bf(u1[i]);
          xa1[4 + i] = (short)f2bf(v1[i]);
        }
      }
#pragma unroll
      for (int g = 0; g < 3; ++g) {
        const unsigned short* Wl = Rreg + g * 4096;
#pragma unroll
        for (int nt = 0; nt < 4; ++nt) {
          const short8 b0 = *reinterpret_cast<const short8*>(Wl + quad * 512 + (nt * 16 + ln) * 8);
          const short8 b1 = *reinterpret_cast<const short8*>(Wl + (4 + quad) * 512 + (nt * 16 + ln) * 8);
          float4v acc = {0.f, 0.f, 0.f, 0.f};
          acc = MFMA16(xa0, b0, acc);
          acc = MFMA16(xa1, b1, acc);
          // D-frag: element (row = mt*16 + quad*4 + r, col e = nt*16 + ln)
          if (g == 0) {
            // Q: A-operand swizzle (channel-contiguous): (e>>3)*4096 + row*8 + (e&7)
            const int ehi = nt * 2 + (ln >> 3);
            const int elo = ln & 7;
#pragma unroll
            for (int r = 0; r < 4; ++r)
              qb[ehi * 4096 + (mt * 16 + quad * 4 + r) * 8 + elo] = f2bf(acc[r]);
          } else if (g == 1) {
            // K: B-operand swizzle for QK^T (channel-contiguous)
            const int ehi = nt * 2 + (ln >> 3);
            const int elo = ln & 7;
#pragma unroll
            for (int r = 0; r < 4; ++r)
              Ksw[ehi * 4096 + (mt * 16 + quad * 4 + r) * 8 + elo] = f2bf(acc[r]);
          } else {
            // V: B-operand swizzle for PV (POSITION-contiguous):
            //    (row>>3)*512 + e*8 + (row&7); rows r=0..3 are consecutive -> packed write
            short4v pk;
#pragma unroll
            for (int r = 0; r < 4; ++r) pk[r] = (short)f2bf(acc[r]);
            const int vbase =
                (mt * 2 + (quad >> 1)) * 512 + (nt * 16 + ln) * 8 + (quad & 1) * 4;
            *reinterpret_cast<short4v*>(Vsw + vbase) = pk;
          }
        }
      }
    }
    __syncthreads();

    // ---- phase 2/3: per-wave Q-tiles: scores -> softmax -> PV -> dense ----
    unsigned short* buf = Rreg + wv * 1152;  // 16 x 72 bf16 repack buffer
#pragma unroll 1
    for (int qi = 0; qi < 4; ++qi) {
      const int qt = wv + qi * 8;
      const short8 q0 = *reinterpret_cast<const short8*>(qb + quad * 4096 + (qt * 16 + ln) * 8);
      const short8 q1 = *reinterpret_cast<const short8*>(qb + (4 + quad) * 4096 + (qt * 16 + ln) * 8);

      // S = Q K^T, 16 x 512, D-frags
      float4v s[32];
#pragma unroll
      for (int nt = 0; nt < 32; ++nt) {
        const short8 k0 = *reinterpret_cast<const short8*>(Ksw + quad * 4096 + (nt * 16 + ln) * 8);
        const short8 k1 = *reinterpret_cast<const short8*>(Ksw + (4 + quad) * 4096 + (nt * 16 + ln) * 8);
        float4v acc = {0.f, 0.f, 0.f, 0.f};
        acc = MFMA16(q0, k0, acc);
        acc = MFMA16(q1, k1, acc);
        s[nt] = acc;
      }

      // row max (row = quad*4+r is replicated across the quad's 16 lanes)
      float mx[4] = {-3.0e38f, -3.0e38f, -3.0e38f, -3.0e38f};
#pragma unroll
      for (int nt = 0; nt < 32; ++nt)
#pragma unroll
        for (int r = 0; r < 4; ++r) mx[r] = fmaxf(mx[r], s[nt][r]);
#pragma unroll
      for (int dd = 1; dd < 16; dd <<= 1)
#pragma unroll
        for (int r = 0; r < 4; ++r) mx[r] = fmaxf(mx[r], __shfl_xor(mx[r], dd, 64));

      float sum[4] = {0.f, 0.f, 0.f, 0.f};
      float4v o[4];
#pragma unroll
      for (int i = 0; i < 4; ++i) o[i] = (float4v){0.f, 0.f, 0.f, 0.f};

      // PV: 16 chunks of 32 cols, P repacked D-layout -> A-layout via wave-local LDS
#pragma unroll
      for (int kc = 0; kc < 16; ++kc) {
#pragma unroll
        for (int t2 = 0; t2 < 2; ++t2) {
          const int nt = kc * 2 + t2;
#pragma unroll
          for (int r = 0; r < 4; ++r) {
            const float p = __expf((s[nt][r] - mx[r]) * 0.125f);
            sum[r] += p;
            buf[(quad * 4 + r) * 72 + t2 * 16 + ln] = f2bf(p);
          }
        }
        asm volatile("s_waitcnt lgkmcnt(0)" ::: "memory");
        const short8 pa = *reinterpret_cast<const short8*>(buf + ln * 72 + quad * 8);
#pragma unroll
        for (int nto = 0; nto < 4; ++nto) {
          // V B-frag: V[m = kc*32 + quad*8 + j][d' = nto*16 + ln]
          const short8 vf =
              *reinterpret_cast<const short8*>(Vsw + (kc * 4 + quad) * 512 + (nto * 16 + ln) * 8);
          o[nto] = MFMA16(pa, vf, o[nto]);
        }
      }

      // row sums -> normalize O
#pragma unroll
      for (int dd = 1; dd < 16; dd <<= 1)
#pragma unroll
        for (int r = 0; r < 4; ++r) sum[r] += __shfl_xor(sum[r], dd, 64);
      float inv[4];
#pragma unroll
      for (int r = 0; r < 4; ++r) inv[r] = 1.0f / sum[r];

      // O (16x64) -> A-layout via buf
#pragma unroll
      for (int nto = 0; nto < 4; ++nto)
#pragma unroll
        for (int r = 0; r < 4; ++r)
          buf[(quad * 4 + r) * 72 + nto * 16 + ln] = f2bf(o[nto][r] * inv[r]);
      asm volatile("s_waitcnt lgkmcnt(0)" ::: "memory");
      const short8 a0 = *reinterpret_cast<const short8*>(buf + ln * 72 + quad * 8);
      const short8 a1 = *reinterpret_cast<const short8*>(buf + ln * 72 + 32 + quad * 8);

      // dense: O @ Wd (+bias in final branch), epilogue
#pragma unroll
      for (int nt = 0; nt < 4; ++nt) {
        const short8 w0 = *reinterpret_cast<const short8*>(Wdsw + quad * 512 + (nt * 16 + ln) * 8);
        const short8 w1 = *reinterpret_cast<const short8*>(Wdsw + (4 + quad) * 512 + (nt * 16 + ln) * 8);
        float4v d4 = {0.f, 0.f, 0.f, 0.f};
        d4 = MFMA16(a0, w0, d4);
        d4 = MFMA16(a1, w1, d4);
        const int m0 = qt * 16 + quad * 4;
        const int col = nt * 16 + ln;
        if (br == 0) {
          // park temporal branch result (sans bias) in d_out
#pragma unroll
          for (int r = 0; r < 4; ++r) outb[(m0 + r) * 64 + col] = d4[r];
        } else {
#pragma unroll
          for (int r = 0; r < 4; ++r) {
            const float z = outb[(m0 + r) * 64 + col] + d4[r] + bdsum[nt];
            const float gate = 1.0f / (1.0f + __expf(-z));
            outb[(m0 + r) * 64 + col] = xb[(m0 + r) * 64 + col] * gate;
          }
        }
      }
    }
    __syncthreads();  // protect Rreg/Ksw/Vsw/qb before next branch restages
  }
}

extern "C" void kernel_launch(void* const* d_in, const int* in_sizes, int n_in,
                              void* d_out, int out_size, void* d_ws, size_t ws_size,
                              hipStream_t stream) {
  const float* x = (const float*)d_in[0];
  const float* Wq_t = (const float*)d_in[1];
  const float* Wk_t = (const float*)d_in[2];
  const float* Wv_t = (const float*)d_in[3];
  const float* Wq_s = (const float*)d_in[4];
  const float* Wk_s = (const float*)d_in[5];
  const float* Wv_s = (const float*)d_in[6];
  const float* Wd_t = (const float*)d_in[7];
  const float* bd_t = (const float*)d_in[8];
  const float* Wd_s = (const float*)d_in[9];
  const float* bd_s = (const float*)d_in[10];
  float* out = (float*)d_out;
  unsigned short* qws = (unsigned short*)d_ws;  // needs 256*512*64*2 = 16 MiB

  hipFuncSetAttribute(reinterpret_cast<const void*>(ts_attn_fused),
                      hipFuncAttributeMaxDynamicSharedMemorySize, LDS_TOTAL_BYTES);
  ts_attn_fused<<<dim3(256), dim3(kThreads), LDS_TOTAL_BYTES, stream>>>(
      x, Wq_t, Wk_t, Wv_t, Wq_s, Wk_s, Wv_s, Wd_t, bd_t, Wd_s, bd_s, out, qws);
}